// Round 5
// baseline (25713.843 us; speedup 1.0000x reference)
//
#include <hip/hip_runtime.h>
#include <hip/hip_bf16.h>

#define T_LEN 2048
#define DIN   128
#define NH    256
#define G4H   1024
#define DOUT  128

typedef float  f32x4  __attribute__((ext_vector_type(4)));
typedef __bf16 bf16x8 __attribute__((ext_vector_type(8)));

#define AL(p)    __hip_atomic_load((p),  __ATOMIC_RELAXED, __HIP_MEMORY_SCOPE_AGENT)
#define AS(p, v) __hip_atomic_store((p), (v), __ATOMIC_RELAXED, __HIP_MEMORY_SCOPE_AGENT)
// compiler-only ordering fence: keep relaxed data loads AFTER the spin-exit
#define CBAR()   asm volatile("" ::: "memory")

static __device__ __forceinline__ float sigf(float x) { return 1.0f / (1.0f + __expf(-x)); }
static __device__ __forceinline__ float tanh_(float x) {
    float ax = fabsf(x);
    float e  = __expf(-2.0f * ax);
    float r  = (1.0f - e) / (1.0f + e);
    return x < 0.0f ? -r : r;
}

// ws layout:
//   [0,    4096)  : unsigned cnt[4][2], stride 256 B   (cnt[bg][half])
//   [4096, 69632) : ushort hbuf[2][4][2][16][128]      (slot, bg, half, row, col) = 64 KiB
//
// Grid 16 x 512thr. bg = id&7 (>=4 idle), half = id>>3.
// 8 waves/block; wave w owns global units [half*128 + w*16, +16) x 4 gates.
// MFMA 16x16x32 maps (verified r1/r3): A row=l&15(batch), A k=(l>>4)*8+e;
// B col=l&15(unit), k same; C col=l&15, row=4*(l>>4)+reg -> lane-local cell update.
// Fence-free exchange: payload + flags are relaxed agent atomics (lowered with
// sc1 -> served at the Infinity-Cache coherence point; no buffer_wbl2/inv).
// Writer: data stores -> s_waitcnt vmcnt(0) -> __syncthreads -> tid0 cnt=t.
// Reader: poll cnt>=t -> compiler barrier -> data loads (issued in order, sc1).
__global__ __launch_bounds__(512, 2) void lstm_scan(
    const float* __restrict__ x,   const float* __restrict__ Wx,
    const float* __restrict__ Wh,  const float* __restrict__ bias,
    const float* __restrict__ fcw, const float* __restrict__ fcb,
    float* __restrict__ out, void* __restrict__ ws)
{
    const int id = blockIdx.x;
    const int bg = id & 7;
    if (bg >= 4) return;
    const int half = id >> 3;           // 0 or 1
    const int tid  = threadIdx.x;
    const int w    = tid >> 6;          // wave 0..7
    const int l    = tid & 63;
    const int lu   = l & 15;
    const int lk   = l >> 4;
    const int ub   = half * 128 + w * 16;   // first global unit owned by this wave

    unsigned*       cnt_me = (unsigned*)ws + (bg * 2 + half) * 64;
    unsigned*       cnt_pa = (unsigned*)ws + (bg * 2 + (1 - half)) * 64;
    unsigned short* hbuf   = (unsigned short*)((char*)ws + 4096);
    #define HOFF(s, b, hf) ((size_t)((((s) * 4 + (b)) * 2 + (hf))) * 2048)

    __shared__ __align__(16) __bf16 hls[2][16 * 128];   // own half, XOR-swizzled rows
    __shared__ float hsm[16 * 256];

    // ---- register-resident weights (bf16 B-fragments, this wave's 64 gate-cols) ----
    bf16x8 whf[8][4];
    #pragma unroll
    for (int kt = 0; kt < 8; ++kt)
        #pragma unroll
        for (int g = 0; g < 4; ++g) {
            bf16x8 f;
            #pragma unroll
            for (int e = 0; e < 8; ++e)
                f[e] = (__bf16)Wh[(kt * 32 + lk * 8 + e) * G4H + g * 256 + ub + lu];
            whf[kt][g] = f;
        }
    bf16x8 wxf[4][4];
    #pragma unroll
    for (int kt = 0; kt < 4; ++kt)
        #pragma unroll
        for (int g = 0; g < 4; ++g) {
            bf16x8 f;
            #pragma unroll
            for (int e = 0; e < 8; ++e)
                f[e] = (__bf16)Wx[(kt * 32 + lk * 8 + e) * G4H + g * 256 + ub + lu];
            wxf[kt][g] = f;
        }
    float bv[4];
    #pragma unroll
    for (int g = 0; g < 4; ++g) bv[g] = bias[g * 256 + ub + lu];

    // h_0 = 0 (own LDS half; hbuf/cnt zeroed by host memset)
    for (int i = tid; i < 16 * 128; i += 512) hls[0][i] = (__bf16)0.0f;

    const float* xrow = x + (size_t)(bg * 16 + lu) * (size_t)(T_LEN * DIN);

    float cc[4] = {0.f, 0.f, 0.f, 0.f};
    float hv[4] = {0.f, 0.f, 0.f, 0.f};

    for (int t = 0; t < T_LEN; ++t) {
        // drain my h-publish stores, then block-wide barrier, then publish flag
        asm volatile("s_waitcnt vmcnt(0)" ::: "memory");
        __syncthreads();
        if (tid == 0) AS(cnt_me, (unsigned)t);   // "my h_t is globally visible"

        // ---- x_t: load f32, convert, 16 MFMAs (independent of h -> hides sync) ----
        const float* xp = xrow + (size_t)t * DIN;
        bf16x8 xa[4];
        #pragma unroll
        for (int kt = 0; kt < 4; ++kt) {
            f32x4 u = *(const f32x4*)(xp + kt * 32 + lk * 8);
            f32x4 v = *(const f32x4*)(xp + kt * 32 + lk * 8 + 4);
            bf16x8 a;
            #pragma unroll
            for (int e = 0; e < 4; ++e) { a[e] = (__bf16)u[e]; a[e + 4] = (__bf16)v[e]; }
            xa[kt] = a;
        }

        f32x4 acc[4];
        #pragma unroll
        for (int g = 0; g < 4; ++g) { f32x4 a = {bv[g], bv[g], bv[g], bv[g]}; acc[g] = a; }

        #pragma unroll
        for (int kt = 0; kt < 4; ++kt)
            #pragma unroll
            for (int g = 0; g < 4; ++g)
                acc[g] = __builtin_amdgcn_mfma_f32_16x16x32_bf16(xa[kt], wxf[kt][g], acc[g], 0, 0, 0);

        // ---- own half of h_t from LDS (16 MFMAs) ----
        #pragma unroll
        for (int kt = 0; kt < 4; ++kt) {
            int byte = (lu * 256 + kt * 64 + lk * 16) ^ ((lu & 7) << 4);
            bf16x8 ha = *(const bf16x8*)((const char*)hls[t & 1] + byte);
            #pragma unroll
            for (int g = 0; g < 4; ++g)
                acc[g] = __builtin_amdgcn_mfma_f32_16x16x32_bf16(ha, whf[half * 4 + kt][g], acc[g], 0, 0, 0);
        }

        // ---- partner half: poll flag, then (ordered) read h via relaxed atomics ----
        while (AL(cnt_pa) < (unsigned)t) {}
        CBAR();
        const unsigned short* rb = hbuf + HOFF(t & 1, bg, 1 - half);
        union { unsigned long long q[2]; bf16x8 v; } ru[4];
        #pragma unroll
        for (int kt = 0; kt < 4; ++kt) {
            const unsigned long long* rp =
                (const unsigned long long*)(rb + lu * 128 + kt * 32 + lk * 8);
            ru[kt].q[0] = AL(rp);
            ru[kt].q[1] = AL(rp + 1);
        }
        #pragma unroll
        for (int kt = 0; kt < 4; ++kt)
            #pragma unroll
            for (int g = 0; g < 4; ++g)
                acc[g] = __builtin_amdgcn_mfma_f32_16x16x32_bf16(ru[kt].v, whf[(1 - half) * 4 + kt][g], acc[g], 0, 0, 0);

        // ---- gates + cell update (lane-local); publish h_{t+1} ----
        unsigned short* wb = hbuf + HOFF((t + 1) & 1, bg, half);
        #pragma unroll
        for (int r = 0; r < 4; ++r) {
            float iv = sigf(acc[0][r]);
            float fv = sigf(acc[1][r]);
            float gv = tanh_(acc[2][r]);
            float ov = sigf(acc[3][r]);
            cc[r] = fv * cc[r] + iv * gv;
            hv[r] = ov * tanh_(cc[r]);
            __bf16 hb16 = (__bf16)hv[r];
            union { __bf16 b; unsigned short u; } cv; cv.b = hb16;
            int m = lk * 4 + r;
            AS(wb + m * 128 + w * 16 + lu, cv.u);                       // global (partner)
            int byte = (m * 256 + (w * 16 + lu) * 2) ^ ((m & 7) << 4);  // LDS (own block)
            *(__bf16*)((char*)hls[(t + 1) & 1] + byte) = hb16;
        }
    }

    // final publish: h_T is in slot 0; flag = T_LEN
    asm volatile("s_waitcnt vmcnt(0)" ::: "memory");
    __syncthreads();
    if (tid == 0) AS(cnt_me, (unsigned)T_LEN);

    // ---- FC: assemble full h_T (own f32 regs + partner bf16), then GEMV ----
    #pragma unroll
    for (int r = 0; r < 4; ++r) hsm[(lk * 4 + r) * 256 + ub + lu] = hv[r];

    while (AL(cnt_pa) < (unsigned)T_LEN) {}
    CBAR();
    {
        const unsigned short* rb = hbuf + HOFF(0, bg, 1 - half);
        int i = tid;                         // 512 ulls: 16 rows x 32 ulls/row
        unsigned long long q = AL((const unsigned long long*)rb + i);
        union { unsigned long long q; __bf16 h[4]; } u2; u2.q = q;
        int row = i >> 5;                    // 128 ushorts = 32 ulls per row
        int c0  = (i & 31) * 4;
        #pragma unroll
        for (int e = 0; e < 4; ++e)
            hsm[row * 256 + (1 - half) * 128 + c0 + e] = (float)u2.h[e];
    }
    __syncthreads();

    for (int idx = tid; idx < 16 * 64; idx += 512) {
        int m = idx >> 6;
        int d = half * 64 + (idx & 63);
        float s = fcb[d];
        for (int j = 0; j < NH; ++j) s += hsm[m * 256 + j] * fcw[j * DOUT + d];
        out[(bg * 16 + m) * DOUT + d] = s;
    }
    #undef HOFF
}

extern "C" void kernel_launch(void* const* d_in, const int* in_sizes, int n_in,
                              void* d_out, int out_size, void* d_ws, size_t ws_size,
                              hipStream_t stream) {
    (void)in_sizes; (void)n_in; (void)ws_size; (void)out_size;
    const float* x   = (const float*)d_in[0];
    const float* Wx  = (const float*)d_in[1];
    const float* Wh  = (const float*)d_in[2];
    const float* b   = (const float*)d_in[3];
    const float* fcw = (const float*)d_in[4];
    const float* fcb = (const float*)d_in[5];
    float* out = (float*)d_out;

    // zero counters + h ping-pong (h0 = 0): 4096 + 65536 bytes
    hipMemsetAsync(d_ws, 0, 69632, stream);
    hipLaunchKernelGGL(lstm_scan, dim3(16), dim3(512), 0, stream,
                       x, Wx, Wh, b, fcw, fcb, out, d_ws);
}

// Round 6
// 14723.906 us; speedup vs baseline: 1.7464x; 1.7464x over previous
//
#include <hip/hip_runtime.h>
#include <hip/hip_bf16.h>

#define T_LEN 2048
#define DIN   128
#define NH    256
#define G4H   1024
#define DOUT  128

typedef float  f32x4  __attribute__((ext_vector_type(4)));
typedef __bf16 bf16x8 __attribute__((ext_vector_type(8)));
typedef unsigned int u32;
typedef unsigned long long u64;

#define AL64(p)   __hip_atomic_load((const u64*)(p), __ATOMIC_RELAXED, __HIP_MEMORY_SCOPE_AGENT)
#define AL32(p)   __hip_atomic_load((const u32*)(p), __ATOMIC_RELAXED, __HIP_MEMORY_SCOPE_AGENT)
#define AS32(p,v) __hip_atomic_store((u32*)(p), (v), __ATOMIC_RELAXED, __HIP_MEMORY_SCOPE_AGENT)
#define CBAR()    asm volatile("" ::: "memory")

static __device__ __forceinline__ float sigf(float x) { return 1.0f / (1.0f + __expf(-x)); }
static __device__ __forceinline__ float tanh_(float x) {
    float ax = fabsf(x);
    float e  = __expf(-2.0f * ax);
    float r  = (1.0f - e) / (1.0f + e);
    return x < 0.0f ? -r : r;
}

// ws: u32 hb[2][4][16][256] = 128 KiB. Word = (tag << 16) | bf16bits(h), where
// tag = t for h_t. memset(0) == valid h_0 (tag 0, value 0). 32-bit stores are
// single-copy atomic -> tag+payload consistent; NO flags, NO fences, NO barriers
// in the scan loop. Slot = t&1; tags in a slot are strictly increasing (t, t+2,..)
// and a writer publishes tag t+2 only after observing every block's tag t+1
// words, which data-depend on their completed tag-t reads -> no lost updates.
//
// Grid 32 x 256 thr; bg = id&7 (>=4 idle -> exit), cb = id>>3. Round-robin
// dispatch puts a bg's 4 blocks {bg, bg+8, bg+16, bg+24} on one XCD (L2/x reuse).
// 4 waves/block; wave w owns gate-cols for units [cb*64 + w*16, +16) x 4 gates.
// MFMA 16x16x32 maps (verified r1/r3): A row=l&15(batch), A k=(l>>4)*8+e;
// B col=l&15(unit), k same; C col=l&15, row=4*(l>>4)+reg -> lane-local cell update.
// launch_bounds(256,1): r3-proven no-spill config (VGPR cap 512; need ~300).
__global__ __launch_bounds__(256, 1) void lstm_scan(
    const float* __restrict__ x,   const float* __restrict__ Wx,
    const float* __restrict__ Wh,  const float* __restrict__ bias,
    const float* __restrict__ fcw, const float* __restrict__ fcb,
    float* __restrict__ out, void* __restrict__ ws)
{
    const int id = blockIdx.x;
    const int bg = id & 7;
    if (bg >= 4) return;
    const int cb  = id >> 3;            // 0..3
    const int tid = threadIdx.x;
    const int w   = tid >> 6;           // wave 0..3
    const int l   = tid & 63;
    const int lu  = l & 15;
    const int lk  = l >> 4;
    const int ub  = cb * 64 + w * 16;   // first unit owned by this wave

    u32* hb = (u32*)ws;                 // [slot][bg][row16][col256]
    #define PANEL(s, b) ((size_t)(((s) * 4 + (b))) * 4096)

    // ---- register-resident weights (bf16 B-fragments, this wave's 64 gate-cols) ----
    bf16x8 whf[8][4];
    #pragma unroll
    for (int kt = 0; kt < 8; ++kt)
        #pragma unroll
        for (int g = 0; g < 4; ++g) {
            bf16x8 f;
            #pragma unroll
            for (int e = 0; e < 8; ++e)
                f[e] = (__bf16)Wh[(kt * 32 + lk * 8 + e) * G4H + g * 256 + ub + lu];
            whf[kt][g] = f;
        }
    bf16x8 wxf[4][4];
    #pragma unroll
    for (int kt = 0; kt < 4; ++kt)
        #pragma unroll
        for (int g = 0; g < 4; ++g) {
            bf16x8 f;
            #pragma unroll
            for (int e = 0; e < 8; ++e)
                f[e] = (__bf16)Wx[(kt * 32 + lk * 8 + e) * G4H + g * 256 + ub + lu];
            wxf[kt][g] = f;
        }
    float bv[4];
    #pragma unroll
    for (int g = 0; g < 4; ++g) bv[g] = bias[g * 256 + ub + lu];

    const float* xrow = x + (size_t)(bg * 16 + lu) * (size_t)(T_LEN * DIN);

    float cc[4] = {0.f, 0.f, 0.f, 0.f};
    float hv[4] = {0.f, 0.f, 0.f, 0.f};

    for (int t = 0; t < T_LEN; ++t) {
        // ---- issue h_t tagged loads first (longest latency) ----
        const u32* rp = hb + PANEL(t & 1, bg) + lu * 256;   // row lu
        u64 q[8][4];
        #pragma unroll
        for (int kt = 0; kt < 8; ++kt)
            #pragma unroll
            for (int j = 0; j < 4; ++j)
                q[kt][j] = AL64(rp + kt * 32 + lk * 8 + j * 2);
        CBAR();

        // ---- x_t: load f32, convert, 16 MFMAs (useful work while h lands) ----
        const float* xp = xrow + (size_t)t * DIN;
        f32x4 acc[4];
        #pragma unroll
        for (int g = 0; g < 4; ++g) { f32x4 a = {bv[g], bv[g], bv[g], bv[g]}; acc[g] = a; }
        #pragma unroll
        for (int kt = 0; kt < 4; ++kt) {
            f32x4 u = *(const f32x4*)(xp + kt * 32 + lk * 8);
            f32x4 v = *(const f32x4*)(xp + kt * 32 + lk * 8 + 4);
            bf16x8 a;
            #pragma unroll
            for (int e = 0; e < 4; ++e) { a[e] = (__bf16)u[e]; a[e + 4] = (__bf16)v[e]; }
            #pragma unroll
            for (int g = 0; g < 4; ++g)
                acc[g] = __builtin_amdgcn_mfma_f32_16x16x32_bf16(a, wxf[kt][g], acc[g], 0, 0, 0);
        }

        // ---- poll: all 32 words must carry tag t; retry reloads all ----
        {
            const u64 pat = ((u64)(u32)t << 16) | ((u64)(u32)t << 48);
            for (;;) {
                u64 bad = 0;
                #pragma unroll
                for (int kt = 0; kt < 8; ++kt)
                    #pragma unroll
                    for (int j = 0; j < 4; ++j)
                        bad |= (q[kt][j] ^ pat) & 0xFFFF0000FFFF0000ull;
                if (bad == 0) break;
                #pragma unroll
                for (int kt = 0; kt < 8; ++kt)
                    #pragma unroll
                    for (int j = 0; j < 4; ++j)
                        q[kt][j] = AL64(rp + kt * 32 + lk * 8 + j * 2);
                CBAR();
            }
        }

        // ---- unpack h fragments, 32 wh MFMAs ----
        #pragma unroll
        for (int kt = 0; kt < 8; ++kt) {
            union { unsigned short u[8]; bf16x8 v; } fa;
            #pragma unroll
            for (int j = 0; j < 4; ++j) {
                u64 qq = q[kt][j];
                fa.u[2 * j]     = (unsigned short)qq;
                fa.u[2 * j + 1] = (unsigned short)(qq >> 32);
            }
            #pragma unroll
            for (int g = 0; g < 4; ++g)
                acc[g] = __builtin_amdgcn_mfma_f32_16x16x32_bf16(fa.v, whf[kt][g], acc[g], 0, 0, 0);
        }

        // ---- gates + cell update (lane-local); publish tagged h_{t+1} ----
        u32* wb = hb + PANEL((t + 1) & 1, bg);
        const u32 tg1 = (u32)(t + 1) << 16;
        #pragma unroll
        for (int r = 0; r < 4; ++r) {
            float iv = sigf(acc[0][r]);
            float fv = sigf(acc[1][r]);
            float gv = tanh_(acc[2][r]);
            float ov = sigf(acc[3][r]);
            cc[r] = fv * cc[r] + iv * gv;
            hv[r] = ov * tanh_(cc[r]);
            union { __bf16 b; unsigned short u; } cv; cv.b = (__bf16)hv[r];
            AS32(wb + (lk * 4 + r) * 256 + ub + lu, tg1 | (u32)cv.u);
        }
    }

    // ---- FC epilogue: poll h_T (tag T_LEN, slot 0), GEMV ----
    __shared__ float hsm[16 * 256];
    const u32* fb = hb + PANEL(T_LEN & 1, bg);
    for (int i = tid; i < 4096; i += 256) {
        u32 qv;
        do { qv = AL32(fb + i); CBAR(); } while ((qv >> 16) != (u32)T_LEN);
        union { unsigned short u; __bf16 b; } cv; cv.u = (unsigned short)(qv & 0xffff);
        hsm[i] = (float)cv.b;
    }
    __syncthreads();
    // patch own 64 cols with full-precision f32 h
    #pragma unroll
    for (int r = 0; r < 4; ++r) hsm[(lk * 4 + r) * 256 + ub + lu] = hv[r];
    __syncthreads();

    for (int idx = tid; idx < 16 * 32; idx += 256) {
        int m = idx >> 5;
        int d = cb * 32 + (idx & 31);
        float s = fcb[d];
        for (int j = 0; j < NH; ++j) s += hsm[m * 256 + j] * fcw[j * DOUT + d];
        out[(bg * 16 + m) * DOUT + d] = s;
    }
    #undef PANEL
}

extern "C" void kernel_launch(void* const* d_in, const int* in_sizes, int n_in,
                              void* d_out, int out_size, void* d_ws, size_t ws_size,
                              hipStream_t stream) {
    (void)in_sizes; (void)n_in; (void)ws_size; (void)out_size;
    const float* x   = (const float*)d_in[0];
    const float* Wx  = (const float*)d_in[1];
    const float* Wh  = (const float*)d_in[2];
    const float* b   = (const float*)d_in[3];
    const float* fcw = (const float*)d_in[4];
    const float* fcb = (const float*)d_in[5];
    float* out = (float*)d_out;

    // zero tagged h buffer: tag 0 + value 0 == valid h_0
    hipMemsetAsync(d_ws, 0, 131072, stream);
    hipLaunchKernelGGL(lstm_scan, dim3(32), dim3(256), 0, stream,
                       x, Wx, Wh, b, fcw, fcb, out, d_ws);
}

// Round 7
// 7493.787 us; speedup vs baseline: 3.4314x; 1.9648x over previous
//
#include <hip/hip_runtime.h>
#include <hip/hip_bf16.h>

#define T_LEN 2048
#define DIN   128
#define NH    256
#define G4H   1024
#define DOUT  128

typedef float  f32x4  __attribute__((ext_vector_type(4)));
typedef __bf16 bf16x8 __attribute__((ext_vector_type(8)));
typedef unsigned int u32;
typedef unsigned long long u64;

#define AL64(p)   __hip_atomic_load((const u64*)(p), __ATOMIC_RELAXED, __HIP_MEMORY_SCOPE_AGENT)
#define AL32(p)   __hip_atomic_load((const u32*)(p), __ATOMIC_RELAXED, __HIP_MEMORY_SCOPE_AGENT)
#define AS32(p,v) __hip_atomic_store((u32*)(p), (v), __ATOMIC_RELAXED, __HIP_MEMORY_SCOPE_AGENT)
#define CBAR()    asm volatile("" ::: "memory")

static __device__ __forceinline__ float sigf(float x) { return 1.0f / (1.0f + __expf(-x)); }
static __device__ __forceinline__ float tanh_(float x) {
    float ax = fabsf(x);
    float e  = __expf(-2.0f * ax);
    float r  = (1.0f - e) / (1.0f + e);
    return x < 0.0f ? -r : r;
}

// ws: u32 hb[2][4][16][256] = 128 KiB. Word = (tag<<16) | bf16bits(h_tag col).
// memset(0) == valid h_0. 32-bit stores are single-copy atomic -> tag+payload
// consistent; no flags, no fences, no writer drain. Slot = t&1; per-slot tags
// strictly increase, and a block publishes tag t+1 only after its staging
// threads observed every tag-t word it consumes -> no lost update, no ABA.
//
// Round-7 change vs r6: remote h staged through LDS ONCE per block (3 remote
// quarters, 12 KB, 6 u64 atomics/thread) instead of every wave re-polling its
// full 256 B -> ~16x less coherence-point traffic per retry. Own quarter is
// written straight to LDS (never read back from global). One barrier/step.
//
// Grid 32 x 256 thr; bg = id&7 (>=4 idle -> exit), cb = id>>3.
// 4 waves/block; wave w owns gate-cols for units [cb*64 + w*16, +16) x 4 gates.
// MFMA 16x16x32 maps (verified r1/r3/r6): A row=l&15(batch), A k=(l>>4)*8+e;
// B col=l&15(unit), k same; C col=l&15, row=4*(l>>4)+reg -> lane-local update.
__global__ __launch_bounds__(256, 1) void lstm_scan(
    const float* __restrict__ x,   const float* __restrict__ Wx,
    const float* __restrict__ Wh,  const float* __restrict__ bias,
    const float* __restrict__ fcw, const float* __restrict__ fcb,
    float* __restrict__ out, void* __restrict__ ws)
{
    const int id = blockIdx.x;
    const int bg = id & 7;
    if (bg >= 4) return;
    const int cb  = id >> 3;            // 0..3
    const int tid = threadIdx.x;
    const int w   = tid >> 6;           // wave 0..3
    const int l   = tid & 63;
    const int lu  = l & 15;
    const int lk  = l >> 4;
    const int ub  = cb * 64 + w * 16;   // first unit owned by this wave

    u32* hb = (u32*)ws;                 // [slot][bg][row16][col256]
    #define PANEL(s, b) ((size_t)(((s) * 4 + (b))) * 4096)

    __shared__ __align__(16) __bf16 hsh[2][16 * 256];   // full h panel, XOR-swizzled rows
    __shared__ float hsm[16 * 256];

    // ---- register-resident weights (bf16 B-fragments, this wave's 64 gate-cols) ----
    bf16x8 whf[8][4];
    #pragma unroll
    for (int kt = 0; kt < 8; ++kt)
        #pragma unroll
        for (int g = 0; g < 4; ++g) {
            bf16x8 f;
            #pragma unroll
            for (int e = 0; e < 8; ++e)
                f[e] = (__bf16)Wh[(kt * 32 + lk * 8 + e) * G4H + g * 256 + ub + lu];
            whf[kt][g] = f;
        }
    bf16x8 wxf[4][4];
    #pragma unroll
    for (int kt = 0; kt < 4; ++kt)
        #pragma unroll
        for (int g = 0; g < 4; ++g) {
            bf16x8 f;
            #pragma unroll
            for (int e = 0; e < 8; ++e)
                f[e] = (__bf16)Wx[(kt * 32 + lk * 8 + e) * G4H + g * 256 + ub + lu];
            wxf[kt][g] = f;
        }
    float bv[4];
    #pragma unroll
    for (int g = 0; g < 4; ++g) bv[g] = bias[g * 256 + ub + lu];

    // zero own LDS h_0 (both buffers' own quarter + remote gets staged anyway;
    // just zero everything once)
    for (int i = tid; i < 16 * 256; i += 256) { hsh[0][i] = (__bf16)0.0f; }

    const float* xrow = x + (size_t)(bg * 16 + lu) * (size_t)(T_LEN * DIN);

    // staging geometry: thread copies 4 consecutive words per remote quarter
    const int rowS = tid >> 4;          // 0..15
    const int c4   = (tid & 15) * 4;    // 0..60

    float cc[4] = {0.f, 0.f, 0.f, 0.f};
    float hv[4] = {0.f, 0.f, 0.f, 0.f};

    for (int t = 0; t < T_LEN; ++t) {
        const int s = t & 1;
        const u32* rp = hb + PANEL(s, bg);

        // ---- issue tagged loads of the 3 remote quarters (6 u64/thread) ----
        u64 q[3][2];
        #pragma unroll
        for (int qi = 0; qi < 3; ++qi) {
            int qq = (cb + 1 + qi) & 3;
            const u64* p = (const u64*)(rp + rowS * 256 + qq * 64 + c4);
            q[qi][0] = AL64(p);
            q[qi][1] = AL64(p + 1);
        }
        CBAR();

        // ---- x_t: load f32, convert, 16 MFMAs (in the poll's latency shadow) ----
        const float* xp = xrow + (size_t)t * DIN;
        f32x4 acc[4];
        #pragma unroll
        for (int g = 0; g < 4; ++g) { f32x4 a = {bv[g], bv[g], bv[g], bv[g]}; acc[g] = a; }
        #pragma unroll
        for (int kt = 0; kt < 4; ++kt) {
            f32x4 u = *(const f32x4*)(xp + kt * 32 + lk * 8);
            f32x4 v = *(const f32x4*)(xp + kt * 32 + lk * 8 + 4);
            bf16x8 a;
            #pragma unroll
            for (int e = 0; e < 4; ++e) { a[e] = (__bf16)u[e]; a[e + 4] = (__bf16)v[e]; }
            #pragma unroll
            for (int g = 0; g < 4; ++g)
                acc[g] = __builtin_amdgcn_mfma_f32_16x16x32_bf16(a, wxf[kt][g], acc[g], 0, 0, 0);
        }

        // ---- poll: all 6 u64 must carry tag t in both halves ----
        {
            const u64 pat = ((u64)(u32)t << 16) | ((u64)(u32)t << 48);
            for (;;) {
                u64 bad = 0;
                #pragma unroll
                for (int qi = 0; qi < 3; ++qi) {
                    bad |= (q[qi][0] ^ pat) & 0xFFFF0000FFFF0000ull;
                    bad |= (q[qi][1] ^ pat) & 0xFFFF0000FFFF0000ull;
                }
                if (bad == 0) break;
                #pragma unroll
                for (int qi = 0; qi < 3; ++qi) {
                    int qq = (cb + 1 + qi) & 3;
                    const u64* p = (const u64*)(rp + rowS * 256 + qq * 64 + c4);
                    q[qi][0] = AL64(p);
                    q[qi][1] = AL64(p + 1);
                }
                CBAR();
            }
        }

        // ---- write staged remote quarters to LDS (8 B per quarter) ----
        #pragma unroll
        for (int qi = 0; qi < 3; ++qi) {
            int qq = (cb + 1 + qi) & 3;
            u64 a = q[qi][0], b = q[qi][1];
            u64 packed = (a & 0xffffull) | ((a >> 32) & 0xffffull) << 16
                       | (b & 0xffffull) << 32 | ((b >> 32) & 0xffffull) << 48;
            int byte = (rowS * 512 + (qq * 64 + c4) * 2) ^ ((rowS & 7) << 4);
            *(u64*)((char*)hsh[s] + byte) = packed;
        }
        __syncthreads();

        // ---- 32 wh MFMAs from LDS ----
        #pragma unroll
        for (int kt = 0; kt < 8; ++kt) {
            int byte = (lu * 512 + kt * 64 + lk * 16) ^ ((lu & 7) << 4);
            bf16x8 ha = *(const bf16x8*)((const char*)hsh[s] + byte);
            #pragma unroll
            for (int g = 0; g < 4; ++g)
                acc[g] = __builtin_amdgcn_mfma_f32_16x16x32_bf16(ha, whf[kt][g], acc[g], 0, 0, 0);
        }

        // ---- gates + cell update (lane-local); publish h_{t+1} ----
        u32* wb = hb + PANEL(s ^ 1, bg);
        const u32 tg1 = (u32)(t + 1) << 16;
        #pragma unroll
        for (int r = 0; r < 4; ++r) {
            float iv = sigf(acc[0][r]);
            float fv = sigf(acc[1][r]);
            float gv = tanh_(acc[2][r]);
            float ov = sigf(acc[3][r]);
            cc[r] = fv * cc[r] + iv * gv;
            hv[r] = ov * tanh_(cc[r]);
            __bf16 hb16 = (__bf16)hv[r];
            union { __bf16 b; unsigned short u; } cv; cv.b = hb16;
            int m = lk * 4 + r;
            AS32(wb + m * 256 + ub + lu, tg1 | (u32)cv.u);           // global (remote blocks)
            int byte = (m * 512 + (ub + lu) * 2) ^ ((m & 7) << 4);   // LDS (own block)
            *(__bf16*)((char*)hsh[s ^ 1] + byte) = hb16;
        }
    }

    // ---- FC epilogue (r6-verified): poll h_T (tag T_LEN, slot 0), GEMV ----
    const u32* fb = hb + PANEL(T_LEN & 1, bg);
    for (int i = tid; i < 4096; i += 256) {
        u32 qv;
        do { qv = AL32(fb + i); CBAR(); } while ((qv >> 16) != (u32)T_LEN);
        union { unsigned short u; __bf16 b; } cv; cv.u = (unsigned short)(qv & 0xffff);
        hsm[i] = (float)cv.b;
    }
    __syncthreads();
    // patch own 64 cols with full-precision f32 h
    #pragma unroll
    for (int r = 0; r < 4; ++r) hsm[(lk * 4 + r) * 256 + ub + lu] = hv[r];
    __syncthreads();

    for (int idx = tid; idx < 16 * 32; idx += 256) {
        int m = idx >> 5;
        int d = cb * 32 + (idx & 31);
        float s = fcb[d];
        for (int j = 0; j < NH; ++j) s += hsm[m * 256 + j] * fcw[j * DOUT + d];
        out[(bg * 16 + m) * DOUT + d] = s;
    }
    #undef PANEL
}

extern "C" void kernel_launch(void* const* d_in, const int* in_sizes, int n_in,
                              void* d_out, int out_size, void* d_ws, size_t ws_size,
                              hipStream_t stream) {
    (void)in_sizes; (void)n_in; (void)ws_size; (void)out_size;
    const float* x   = (const float*)d_in[0];
    const float* Wx  = (const float*)d_in[1];
    const float* Wh  = (const float*)d_in[2];
    const float* b   = (const float*)d_in[3];
    const float* fcw = (const float*)d_in[4];
    const float* fcb = (const float*)d_in[5];
    float* out = (float*)d_out;

    // zero tagged h buffer: tag 0 + value 0 == valid h_0
    hipMemsetAsync(d_ws, 0, 131072, stream);
    hipLaunchKernelGGL(lstm_scan, dim3(32), dim3(256), 0, stream,
                       x, Wx, Wh, b, fcw, fcb, out, d_ws);
}